// Round 13
// baseline (131.244 us; speedup 1.0000x reference)
//
#include <hip/hip_runtime.h>
#include <hip/hip_bf16.h>

typedef __attribute__((ext_vector_type(8))) short short8;
typedef __attribute__((ext_vector_type(4))) short short4v;
typedef __attribute__((ext_vector_type(4))) float f32x4;

#define MFMA16(A, B, C) __builtin_amdgcn_mfma_f32_16x16x32_bf16(A, B, C, 0, 0, 0)

#define SEQ 2048
#define DM 512
#define NH 8
#define DK 64
#define NROWS 4096   // B*S
#define DSPLIT 4     // k-splits for den
#define ASPLIT 4     // k-splits for attn_pv
#define NT_D (SEQ / DSPLIT / 64)  // 8 tiles
#define NT_A (SEQ / ASPLIT / 64)  // 8 tiles
#define C1 0.180336880f           // 0.125 * log2(e)

__device__ __forceinline__ short f2bf(float f) {
  union { float f; unsigned u; } x; x.f = f;
  unsigned r = (x.u + 0x7fffu + ((x.u >> 16) & 1u)) >> 16;
  return (short)r;
}
__device__ __forceinline__ float bf2f(short s) {
  union { unsigned u; float f; } x; x.u = ((unsigned)(unsigned short)s) << 16;
  return x.f;
}

// async 16B global -> LDS (wave-uniform LDS base + lane*16; per-lane g addr)
__device__ __forceinline__ void gload_lds16(const short* g, short* l) {
  __builtin_amdgcn_global_load_lds(
      (const __attribute__((address_space(1))) void*)g,
      (__attribute__((address_space(3))) void*)l,
      16, 0, 0);
}

// ---------------------------------------------------------------------------
// Kernel 0: one-time f32 -> bf16 casts. z=0..2: activations (1024 blocks),
// z=3..6: weights (first 128 blocks active).
// ---------------------------------------------------------------------------
__global__ __launch_bounds__(256) void cast_all_kernel(
    const float* __restrict__ q, const float* __restrict__ k, const float* __restrict__ v,
    const float* __restrict__ Wq, const float* __restrict__ Wk,
    const float* __restrict__ Wv, const float* __restrict__ Wo,
    short* __restrict__ qb, short* __restrict__ kb, short* __restrict__ vb,
    short* __restrict__ Wqb, short* __restrict__ Wkb,
    short* __restrict__ Wvb, short* __restrict__ Wob)
{
  int z = blockIdx.z;
  if (z >= 3 && blockIdx.x >= 128) return;
  const float* src;
  short* dst;
  switch (z) {
    case 0: src = q;  dst = qb;  break;
    case 1: src = k;  dst = kb;  break;
    case 2: src = v;  dst = vb;  break;
    case 3: src = Wq; dst = Wqb; break;
    case 4: src = Wk; dst = Wkb; break;
    case 5: src = Wv; dst = Wvb; break;
    default: src = Wo; dst = Wob; break;
  }
  size_t i = ((size_t)blockIdx.x * 256 + threadIdx.x) * 8;
  float4 f0 = *(const float4*)(src + i);
  float4 f1 = *(const float4*)(src + i + 4);
  short8 s;
  s[0] = f2bf(f0.x); s[1] = f2bf(f0.y); s[2] = f2bf(f0.z); s[3] = f2bf(f0.w);
  s[4] = f2bf(f1.x); s[5] = f2bf(f1.y); s[6] = f2bf(f1.z); s[7] = f2bf(f1.w);
  *(short8*)(dst + i) = s;
}

// ---------------------------------------------------------------------------
// Kernel 1: QKV projection, m97-structure: 128x128 tile, BK=32, 4 waves with
// acc[4][4], global_load_lds(16B) staging into linear [128][32] LDS tiles.
// ---------------------------------------------------------------------------
__global__ __launch_bounds__(256) void qkv_proj_kernel(
    const short* __restrict__ qbf, const short* __restrict__ kbf, const short* __restrict__ vbf,
    const short* __restrict__ Wqb, const short* __restrict__ Wkb, const short* __restrict__ Wvb,
    const float* __restrict__ bq, const float* __restrict__ bk, const float* __restrict__ bv,
    short* __restrict__ Qb, short* __restrict__ Kb, short* __restrict__ Vtb)
{
  int z = blockIdx.z;
  const short* X    = (z == 0) ? qbf : (z == 1) ? kbf : vbf;
  const short* W    = (z == 0) ? Wqb : (z == 1) ? Wkb : Wvb;
  const float* bias = (z == 0) ? bq  : (z == 1) ? bk  : bv;

  __shared__ short As[128][32];   // linear (no pad): required by global_load_lds
  __shared__ short Bs[128][32];

  int t = threadIdx.x;
  int lane = t & 63, wave = t >> 6;
  int wr = wave >> 1, wc = wave & 1;
  int fr = lane & 15, fg = lane >> 4;
  int m0 = blockIdx.x * 128, n0 = blockIdx.y * 128;

  // staging geometry: each gload_lds covers 16 rows (64B/row); lane l ->
  // row +l/4, col (l&3)*8. Wave w stages rows w*32..w*32+31 (2 instrs each op).
  int srow = lane >> 2, scol = (lane & 3) * 8;

  f32x4 acc[4][4] = {};

  for (int k0 = 0; k0 < DM; k0 += 32) {
    __syncthreads();
    {
      int rbase = wave * 32;
#pragma unroll
      for (int i = 0; i < 2; i++) {
        const short* ga = X + (size_t)(m0 + rbase + i * 16 + srow) * DM + k0 + scol;
        gload_lds16(ga, &As[rbase + i * 16][0]);
        const short* gb = W + (size_t)(n0 + rbase + i * 16 + srow) * DM + k0 + scol;
        gload_lds16(gb, &Bs[rbase + i * 16][0]);
      }
    }
    __syncthreads();

    short8 af[4], bf[4];
#pragma unroll
    for (int mi = 0; mi < 4; mi++)
      af[mi] = *(const short8*)&As[wr * 64 + mi * 16 + fr][fg * 8];
#pragma unroll
    for (int ni = 0; ni < 4; ni++)
      bf[ni] = *(const short8*)&Bs[wc * 64 + ni * 16 + fr][fg * 8];
#pragma unroll
    for (int mi = 0; mi < 4; mi++)
#pragma unroll
      for (int ni = 0; ni < 4; ni++)
        acc[mi][ni] = MFMA16(af[mi], bf[ni], acc[mi][ni]);
  }

#pragma unroll
  for (int ni = 0; ni < 4; ni++) {
    int col = n0 + wc * 64 + ni * 16 + fr;
    float bval = bias[col];
    int h = col >> 6, dk = col & 63;
#pragma unroll
    for (int mi = 0; mi < 4; mi++)
#pragma unroll
      for (int r = 0; r < 4; r++) {
        int row = m0 + wr * 64 + mi * 16 + fg * 4 + r;
        int bb = row >> 11, s = row & 2047;
        short o = f2bf(acc[mi][ni][r] + bval);
        if (z == 0)      Qb[((size_t)(bb * NH + h) * SEQ + s) * DK + dk] = o;
        else if (z == 1) Kb[((size_t)(bb * NH + h) * SEQ + s) * DK + dk] = o;
        else             Vtb[((size_t)(bb * NH + h) * DK + dk) * SEQ + s] = o;
      }
  }
}

// ---------------------------------------------------------------------------
// Kernel 2a: softmax denominators (M=0), swapped QK (lane owns one q-row).
// ---------------------------------------------------------------------------
__global__ __launch_bounds__(256) void den_kernel(
    const short* __restrict__ Q, const short* __restrict__ K, float* __restrict__ dp)
{
  __shared__ short Ks[64][72];

  int t = threadIdx.x, lane = t & 63, wave = t >> 6;
  int fr = lane & 15, fg = lane >> 4;
  int bh = blockIdx.y, z = blockIdx.z;
  const short* Qh = Q + (size_t)bh * SEQ * DK;
  const short* Kh = K + (size_t)bh * SEQ * DK;
  int q0 = blockIdx.x * 64 + wave * 16;
  const int kbase = z * (SEQ / DSPLIT);

  short8 qa0 = *(const short8*)(Qh + (q0 + fr) * DK + fg * 8);
  short8 qa1 = *(const short8*)(Qh + (q0 + fr) * DK + 32 + fg * 8);

  int r_st = t >> 2, c_st = (t & 3) * 16;

  const short* kp0 = Kh + (size_t)(kbase + r_st) * DK + c_st;
  short8 k_pf0 = *(const short8*)kp0;
  short8 k_pf1 = *(const short8*)(kp0 + 8);

  float esum = 0.f;

  for (int kt = 0; kt < NT_D; kt++) {
    __syncthreads();
    *(short8*)&Ks[r_st][c_st]     = k_pf0;
    *(short8*)&Ks[r_st][c_st + 8] = k_pf1;
    __syncthreads();
    if (kt + 1 < NT_D) {
      const short* kp = Kh + (size_t)(kbase + (kt + 1) * 64 + r_st) * DK + c_st;
      k_pf0 = *(const short8*)kp;
      k_pf1 = *(const short8*)(kp + 8);
    }
#pragma unroll
    for (int ct = 0; ct < 4; ct++) {
      short8 k0v = *(const short8*)&Ks[ct * 16 + fr][fg * 8];
      short8 k1v = *(const short8*)&Ks[ct * 16 + fr][32 + fg * 8];
      f32x4 zz = {0.f, 0.f, 0.f, 0.f};
      zz = MFMA16(k0v, qa0, zz);   // swapped: lane -> q-row fr, k-cols fg*4+r
      zz = MFMA16(k1v, qa1, zz);
#pragma unroll
      for (int r = 0; r < 4; r++)
        esum += __builtin_amdgcn_exp2f(zz[r] * C1);
    }
  }

  esum += __shfl_xor(esum, 16);
  esum += __shfl_xor(esum, 32);
  if (lane < 16)
    dp[((size_t)z * 16 + bh) * SEQ + q0 + lane] = esum;
}

// ---------------------------------------------------------------------------
// Kernel 2b: fused attention, 512 threads / 8 waves per block sharing one
// 64x64 K tile + V tile. Swapped QK MFMA -> exp2 (folded 1/den) -> packed
// b64 P staging -> attn store via LDS transpose (256B f32x4) -> PV.
// ---------------------------------------------------------------------------
__global__ __launch_bounds__(512) void attn_pv_kernel(
    const short* __restrict__ Q, const short* __restrict__ K, const short* __restrict__ Vt,
    const float* __restrict__ dp, float* __restrict__ attn,
    short* __restrict__ ctxp0, short* __restrict__ ctxp3)
{
  __shared__ short Ks[64][72];
  __shared__ short Vs[64][72];
  __shared__ short P[8][16][72];

  int t = threadIdx.x, lane = t & 63, wave = t >> 6;   // wave 0..7
  int fr = lane & 15, fg = lane >> 4;
  int bh = blockIdx.y, z = blockIdx.z;
  const short* Qh = Q + (size_t)bh * SEQ * DK;
  const short* Kh = K + (size_t)bh * SEQ * DK;
  const short* Vh = Vt + (size_t)bh * DK * SEQ;
  int q0 = blockIdx.x * 128 + wave * 16;
  const int kbase = z * (SEQ / ASPLIT);

  short8 qa0 = *(const short8*)(Qh + (q0 + fr) * DK + fg * 8);
  short8 qa1 = *(const short8*)(Qh + (q0 + fr) * DK + 32 + fg * 8);

  // denominator for this lane's q-row (fr); folded into exp2 as +log2(1/d)
  float dsum = 0.f;
#pragma unroll
  for (int zz = 0; zz < DSPLIT; zz++)
    dsum += dp[((size_t)zz * 16 + bh) * SEQ + q0 + fr];
  float lg2r = -__builtin_amdgcn_logf(dsum);

  // staging split across 512 threads: one short8 of K and one of V each
  int r_st = t >> 3, c_st = (t & 7) * 8;
  int rlo = lane >> 4, c4 = (lane & 15) * 4;

  f32x4 oacc[4] = {};

  const short* kp0 = Kh + (size_t)(kbase + r_st) * DK + c_st;
  const short* vp0 = Vh + (size_t)r_st * SEQ + kbase + c_st;
  short8 k_pf = *(const short8*)kp0;
  short8 v_pf = *(const short8*)vp0;

  for (int kt = 0; kt < NT_A; kt++) {
    int kb = kbase + kt * 64;
    __syncthreads();
    *(short8*)&Ks[r_st][c_st] = k_pf;
    *(short8*)&Vs[r_st][c_st] = v_pf;
    __syncthreads();
    if (kt + 1 < NT_A) {
      k_pf = *(const short8*)(Kh + (size_t)(kb + 64 + r_st) * DK + c_st);
      v_pf = *(const short8*)(Vh + (size_t)r_st * SEQ + kb + 64 + c_st);
    }

    // swapped scores + exp2(fold) -> packed b64 P writes (4 per lane)
#pragma unroll
    for (int ct = 0; ct < 4; ct++) {
      short8 k0v = *(const short8*)&Ks[ct * 16 + fr][fg * 8];
      short8 k1v = *(const short8*)&Ks[ct * 16 + fr][32 + fg * 8];
      f32x4 zz = {0.f, 0.f, 0.f, 0.f};
      zz = MFMA16(k0v, qa0, zz);   // lane -> q-row fr, k-cols ct*16+fg*4..+3
      zz = MFMA16(k1v, qa1, zz);
      short4v pk;
#pragma unroll
      for (int r = 0; r < 4; r++)
        pk[r] = f2bf(__builtin_amdgcn_exp2f(zz[r] * C1 + lg2r));
      *(short4v*)&P[wave][fr][ct * 16 + fg * 4] = pk;
    }
    asm volatile("s_waitcnt lgkmcnt(0)" ::: "memory");

    // attn store: 4 instrs, each 4 rows x 256B contiguous
#pragma unroll
    for (int jr = 0; jr < 4; jr++) {
      int row = jr * 4 + rlo;
      short4v pv4 = *(const short4v*)&P[wave][row][c4];
      f32x4 vv = {bf2f(pv4[0]), bf2f(pv4[1]), bf2f(pv4[2]), bf2f(pv4[3])};
      *(f32x4*)&attn[((size_t)(bh * SEQ + q0 + row)) * SEQ + kb + c4] = vv;
    }

    // PV: oacc[dt] += P(16q x 64k) * V^T(64d x 64k); 8 MFMAs
    short8 pa0 = *(const short8*)&P[wave][fr][fg * 8];
    short8 pa1 = *(const short8*)&P[wave][fr][32 + fg * 8];
#pragma unroll
    for (int dt = 0; dt < 4; dt++) {
      short8 v0 = *(const short8*)&Vs[dt * 16 + fr][fg * 8];
      short8 v1 = *(const short8*)&Vs[dt * 16 + fr][32 + fg * 8];
      oacc[dt] = MFMA16(pa0, v0, oacc[dt]);
      oacc[dt] = MFMA16(pa1, v1, oacc[dt]);
    }
  }

  int b = bh >> 3, h = bh & 7;
  short* cbase = (z < 3) ? (ctxp0 + (size_t)z * NROWS * DM) : ctxp3;
#pragma unroll
  for (int dt = 0; dt < 4; dt++)
#pragma unroll
    for (int r = 0; r < 4; r++) {
      int row = q0 + fg * 4 + r;
      cbase[((size_t)b * SEQ + row) * DM + h * 64 + dt * 16 + fr] = f2bf(oacc[dt][r]);
    }
}

// ---------------------------------------------------------------------------
// Kernel 3: output projection + bias + residual -> x (f32).
// A-operand = sum of 4 normalized ctx partials (fused reduce, prefetched).
// ---------------------------------------------------------------------------
__global__ __launch_bounds__(256) void oproj_kernel(
    const short* __restrict__ ctxp0, const short* __restrict__ ctxp3,
    const short* __restrict__ Wob,
    const float* __restrict__ bias, const float* __restrict__ resid,
    float* __restrict__ xout)
{
  const size_t NPART = (size_t)NROWS * DM;
  __shared__ short As[64][40];
  __shared__ short Bs[64][40];

  int t = threadIdx.x;
  int lane = t & 63, wave = t >> 6;
  int wr = wave >> 1, wc = wave & 1;
  int fr = lane & 15, fg = lane >> 4;
  int m0 = blockIdx.x * 64, n0 = blockIdx.y * 64;
  int lrow = t >> 2, lcol = (t & 3) * 8;

  f32x4 acc[2][2] = {};

  size_t ia0 = (size_t)(m0 + lrow) * DM + lcol;
  short8 a_pf0 = *(const short8*)(ctxp0 + ia0);
  short8 a_pf1 = *(const short8*)(ctxp0 + NPART + ia0);
  short8 a_pf2 = *(const short8*)(ctxp0 + 2 * NPART + ia0);
  short8 a_pf3 = *(const short8*)(ctxp3 + ia0);
  short8 b_pf = *(const short8*)(Wob + (size_t)(n0 + lrow) * DM + lcol);

  for (int k0 = 0; k0 < DM; k0 += 32) {
    __syncthreads();
    {
      short8 sv;
#pragma unroll
      for (int j = 0; j < 8; j++)
        sv[j] = f2bf(bf2f(a_pf0[j]) + bf2f(a_pf1[j]) + bf2f(a_pf2[j]) + bf2f(a_pf3[j]));
      *(short8*)&As[lrow][lcol] = sv;
      *(short8*)&Bs[lrow][lcol] = b_pf;
    }
    __syncthreads();
    if (k0 + 32 < DM) {
      size_t ia = (size_t)(m0 + lrow) * DM + k0 + 32 + lcol;
      a_pf0 = *(const short8*)(ctxp0 + ia);
      a_pf1 = *(const short8*)(ctxp0 + NPART + ia);
      a_pf2 = *(const short8*)(ctxp0 + 2 * NPART + ia);
      a_pf3 = *(const short8*)(ctxp3 + ia);
      b_pf = *(const short8*)(Wob + (size_t)(n0 + lrow) * DM + k0 + 32 + lcol);
    }
    short8 a0 = *(const short8*)&As[wr * 32 + fr][fg * 8];
    short8 a1 = *(const short8*)&As[wr * 32 + 16 + fr][fg * 8];
    short8 b0 = *(const short8*)&Bs[wc * 32 + fr][fg * 8];
    short8 b1 = *(const short8*)&Bs[wc * 32 + 16 + fr][fg * 8];
    acc[0][0] = MFMA16(a0, b0, acc[0][0]);
    acc[0][1] = MFMA16(a0, b1, acc[0][1]);
    acc[1][0] = MFMA16(a1, b0, acc[1][0]);
    acc[1][1] = MFMA16(a1, b1, acc[1][1]);
  }

#pragma unroll
  for (int mi = 0; mi < 2; mi++)
#pragma unroll
    for (int ni = 0; ni < 2; ni++)
#pragma unroll
      for (int r = 0; r < 4; r++) {
        int row = m0 + wr * 32 + mi * 16 + fg * 4 + r;
        int col = n0 + wc * 32 + ni * 16 + fr;
        float val = acc[mi][ni][r] + bias[col] + resid[(size_t)row * DM + col];
        xout[(size_t)row * DM + col] = val;
      }
}

// ---------------------------------------------------------------------------
// Kernel 4: LayerNorm over last dim (512). One wave per row.
// ---------------------------------------------------------------------------
__global__ __launch_bounds__(256) void ln_kernel(
    const float* __restrict__ x, const float* __restrict__ gamma,
    const float* __restrict__ beta, float* __restrict__ y)
{
  int row = blockIdx.x * 4 + (threadIdx.x >> 6);
  int lane = threadIdx.x & 63;
  const float4* xr = (const float4*)(x + (size_t)row * DM);
  float4 v0 = xr[lane * 2];
  float4 v1 = xr[lane * 2 + 1];
  float s = v0.x + v0.y + v0.z + v0.w + v1.x + v1.y + v1.z + v1.w;
#pragma unroll
  for (int off = 1; off < 64; off <<= 1) s += __shfl_xor(s, off);
  float mean = s * (1.0f / DM);
  float a0 = v0.x - mean, a1 = v0.y - mean, a2 = v0.z - mean, a3 = v0.w - mean;
  float a4 = v1.x - mean, a5 = v1.y - mean, a6 = v1.z - mean, a7 = v1.w - mean;
  float vs = a0 * a0 + a1 * a1 + a2 * a2 + a3 * a3 + a4 * a4 + a5 * a5 + a6 * a6 + a7 * a7;
#pragma unroll
  for (int off = 1; off < 64; off <<= 1) vs += __shfl_xor(vs, off);
  float rstd = rsqrtf(vs * (1.0f / DM) + 1e-5f);
  const float4* gp = (const float4*)gamma;
  const float4* bp = (const float4*)beta;
  float4 g0 = gp[lane * 2], g1 = gp[lane * 2 + 1];
  float4 b0 = bp[lane * 2], b1 = bp[lane * 2 + 1];
  float4 o0, o1;
  o0.x = a0 * rstd * g0.x + b0.x; o0.y = a1 * rstd * g0.y + b0.y;
  o0.z = a2 * rstd * g0.z + b0.z; o0.w = a3 * rstd * g0.w + b0.w;
  o1.x = a4 * rstd * g1.x + b1.x; o1.y = a5 * rstd * g1.y + b1.y;
  o1.z = a6 * rstd * g1.z + b1.z; o1.w = a7 * rstd * g1.w + b1.w;
  float4* yr = (float4*)(y + (size_t)row * DM);
  yr[lane * 2] = o0;
  yr[lane * 2 + 1] = o1;
}

// ---------------------------------------------------------------------------
extern "C" void kernel_launch(void* const* d_in, const int* in_sizes, int n_in,
                              void* d_out, int out_size, void* d_ws, size_t ws_size,
                              hipStream_t stream)
{
  const float* q     = (const float*)d_in[0];
  const float* k     = (const float*)d_in[1];
  const float* v     = (const float*)d_in[2];
  const float* Wq    = (const float*)d_in[3];
  const float* bq    = (const float*)d_in[4];
  const float* Wk    = (const float*)d_in[5];
  const float* bk    = (const float*)d_in[6];
  const float* Wv    = (const float*)d_in[7];
  const float* bv    = (const float*)d_in[8];
  const float* Wo    = (const float*)d_in[9];
  const float* bo    = (const float*)d_in[10];
  const float* gamma = (const float*)d_in[11];
  const float* beta  = (const float*)d_in[12];

  char* w = (char*)d_ws;
  // [0,12): qbf/kbf/vbf (dead after qkv) -> reused as ctxp partials 0..2
  short* qbf  = (short*)(w);
  short* kbf  = (short*)(w + ((size_t)4  << 20));
  short* vbf  = (short*)(w + ((size_t)8  << 20));
  short* Qb   = (short*)(w + ((size_t)12 << 20));     // [12,16)  [B,H,S,DK]
  short* Kb   = (short*)(w + ((size_t)16 << 20));     // [16,20)
  short* Vtb  = (short*)(w + ((size_t)20 << 20));     // [20,24)  [B,H,DK,S]
  short* Wqb  = (short*)(w + ((size_t)24 << 20));     // [24,24.5)
  short* Wkb  = (short*)(w + ((size_t)24 << 20) + ((size_t)512 << 10));
  short* Wvb  = (short*)(w + ((size_t)25 << 20));
  short* Wob  = (short*)(w + ((size_t)25 << 20) + ((size_t)512 << 10));
  float* denp = (float*)(w + ((size_t)26 << 20));     // [26,26.5) f32 [4][16][SEQ]
  short* ctxp0 = (short*)(w);                         // [ 0,12): partials 0..2
  short* ctxp3 = (short*)(w + ((size_t)27 << 20));    // [27,31): partial 3
  float* xbuf  = (float*)(w + ((size_t)12 << 20));    // [12,20): reuse Qb/Kb (dead)

  float* y = (float*)d_out;
  float* attnp = y + (size_t)NROWS * DM;  // [B,H,S,S]

  cast_all_kernel<<<dim3(1024, 1, 7), 256, 0, stream>>>(q, k, v, Wq, Wk, Wv, Wo,
                                                        qbf, kbf, vbf, Wqb, Wkb, Wvb, Wob);
  qkv_proj_kernel<<<dim3(32, 4, 3), 256, 0, stream>>>(qbf, kbf, vbf, Wqb, Wkb, Wvb,
                                                      bq, bk, bv, Qb, Kb, Vtb);
  den_kernel<<<dim3(32, 16, DSPLIT), 256, 0, stream>>>(Qb, Kb, denp);
  attn_pv_kernel<<<dim3(16, 16, ASPLIT), 512, 0, stream>>>(Qb, Kb, Vtb, denp, attnp,
                                                           ctxp0, ctxp3);
  oproj_kernel<<<dim3(64, 8), 256, 0, stream>>>(ctxp0, ctxp3, Wob, bo, q, xbuf);
  ln_kernel<<<1024, 256, 0, stream>>>(xbuf, gamma, beta, y);
}

// Round 14
// 130.722 us; speedup vs baseline: 1.0040x; 1.0040x over previous
//
#include <hip/hip_runtime.h>
#include <hip/hip_bf16.h>

typedef __attribute__((ext_vector_type(8))) short short8;
typedef __attribute__((ext_vector_type(4))) short short4v;
typedef __attribute__((ext_vector_type(4))) float f32x4;

#define MFMA16(A, B, C) __builtin_amdgcn_mfma_f32_16x16x32_bf16(A, B, C, 0, 0, 0)

#define SEQ 2048
#define DM 512
#define NH 8
#define DK 64
#define NROWS 4096   // B*S
#define DSPLIT 4     // k-splits for den
#define ASPLIT 4     // k-splits for attn_pv
#define NT_D (SEQ / DSPLIT / 64)  // 8 tiles
#define NT_A (SEQ / ASPLIT / 64)  // 8 tiles
#define C1 0.180336880f           // 0.125 * log2(e)

__device__ __forceinline__ short f2bf(float f) {
  union { float f; unsigned u; } x; x.f = f;
  unsigned r = (x.u + 0x7fffu + ((x.u >> 16) & 1u)) >> 16;
  return (short)r;
}
__device__ __forceinline__ float bf2f(short s) {
  union { unsigned u; float f; } x; x.u = ((unsigned)(unsigned short)s) << 16;
  return x.f;
}
__device__ __forceinline__ short8 cvt8(float4 f0, float4 f1) {
  short8 s;
  s[0] = f2bf(f0.x); s[1] = f2bf(f0.y); s[2] = f2bf(f0.z); s[3] = f2bf(f0.w);
  s[4] = f2bf(f1.x); s[5] = f2bf(f1.y); s[6] = f2bf(f1.z); s[7] = f2bf(f1.w);
  return s;
}

// ---------------------------------------------------------------------------
// Kernel 1: QKV projection from f32 inputs (inline cvt), reg-prefetched
// staging. out[n][o] = sum_d X[n][d]*W[o][d] + b[o]
// z=0: Q -> [B,H,S,DK] ; z=1: K -> [B,H,S,DK] ; z=2: V -> [B,H,DK,S] (T)
// ---------------------------------------------------------------------------
__global__ __launch_bounds__(256) void qkv_proj_kernel(
    const float* __restrict__ qin, const float* __restrict__ kin, const float* __restrict__ vin,
    const float* __restrict__ Wq, const float* __restrict__ Wk, const float* __restrict__ Wv,
    const float* __restrict__ bq, const float* __restrict__ bk, const float* __restrict__ bv,
    short* __restrict__ Qb, short* __restrict__ Kb, short* __restrict__ Vtb)
{
  int z = blockIdx.z;
  const float* X    = (z == 0) ? qin : (z == 1) ? kin : vin;
  const float* W    = (z == 0) ? Wq  : (z == 1) ? Wk  : Wv;
  const float* bias = (z == 0) ? bq  : (z == 1) ? bk  : bv;

  __shared__ short As[64][40];
  __shared__ short Bs[64][40];

  int t = threadIdx.x;
  int lane = t & 63, wave = t >> 6;
  int wr = wave >> 1, wc = wave & 1;
  int fr = lane & 15, fg = lane >> 4;
  int m0 = blockIdx.x * 64, n0 = blockIdx.y * 64;
  int lrow = t >> 2, lcol = (t & 3) * 8;

  f32x4 acc[2][2] = {};

  const float* ap = X + (size_t)(m0 + lrow) * DM + lcol;
  const float* bp = W + (size_t)(n0 + lrow) * DM + lcol;
  float4 a0f = *(const float4*)ap,       a1f = *(const float4*)(ap + 4);
  float4 b0f = *(const float4*)bp,       b1f = *(const float4*)(bp + 4);

  for (int k0 = 0; k0 < DM; k0 += 32) {
    __syncthreads();
    *(short8*)&As[lrow][lcol] = cvt8(a0f, a1f);
    *(short8*)&Bs[lrow][lcol] = cvt8(b0f, b1f);
    __syncthreads();
    if (k0 + 32 < DM) {
      const float* an = X + (size_t)(m0 + lrow) * DM + k0 + 32 + lcol;
      const float* bn = W + (size_t)(n0 + lrow) * DM + k0 + 32 + lcol;
      a0f = *(const float4*)an; a1f = *(const float4*)(an + 4);
      b0f = *(const float4*)bn; b1f = *(const float4*)(bn + 4);
    }
    short8 a0 = *(const short8*)&As[wr * 32 + fr][fg * 8];
    short8 a1 = *(const short8*)&As[wr * 32 + 16 + fr][fg * 8];
    short8 b0 = *(const short8*)&Bs[wc * 32 + fr][fg * 8];
    short8 b1 = *(const short8*)&Bs[wc * 32 + 16 + fr][fg * 8];
    acc[0][0] = MFMA16(a0, b0, acc[0][0]);
    acc[0][1] = MFMA16(a0, b1, acc[0][1]);
    acc[1][0] = MFMA16(a1, b0, acc[1][0]);
    acc[1][1] = MFMA16(a1, b1, acc[1][1]);
  }

#pragma unroll
  for (int mi = 0; mi < 2; mi++)
#pragma unroll
    for (int ni = 0; ni < 2; ni++)
#pragma unroll
      for (int r = 0; r < 4; r++) {
        int row = m0 + wr * 32 + mi * 16 + fg * 4 + r;
        int col = n0 + wc * 32 + ni * 16 + fr;
        float val = acc[mi][ni][r] + bias[col];
        int bb = row >> 11, s = row & 2047, h = col >> 6, dk = col & 63;
        short o = f2bf(val);
        if (z == 0)      Qb[((size_t)(bb * NH + h) * SEQ + s) * DK + dk] = o;
        else if (z == 1) Kb[((size_t)(bb * NH + h) * SEQ + s) * DK + dk] = o;
        else             Vtb[((size_t)(bb * NH + h) * DK + dk) * SEQ + s] = o;
      }
}

// ---------------------------------------------------------------------------
// Kernel 2a: softmax denominators (M=0), swapped QK (lane owns one q-row).
// ---------------------------------------------------------------------------
__global__ __launch_bounds__(256) void den_kernel(
    const short* __restrict__ Q, const short* __restrict__ K, float* __restrict__ dp)
{
  __shared__ short Ks[64][72];

  int t = threadIdx.x, lane = t & 63, wave = t >> 6;
  int fr = lane & 15, fg = lane >> 4;
  int bh = blockIdx.y, z = blockIdx.z;
  const short* Qh = Q + (size_t)bh * SEQ * DK;
  const short* Kh = K + (size_t)bh * SEQ * DK;
  int q0 = blockIdx.x * 64 + wave * 16;
  const int kbase = z * (SEQ / DSPLIT);

  short8 qa0 = *(const short8*)(Qh + (q0 + fr) * DK + fg * 8);
  short8 qa1 = *(const short8*)(Qh + (q0 + fr) * DK + 32 + fg * 8);

  int r_st = t >> 2, c_st = (t & 3) * 16;

  const short* kp0 = Kh + (size_t)(kbase + r_st) * DK + c_st;
  short8 k_pf0 = *(const short8*)kp0;
  short8 k_pf1 = *(const short8*)(kp0 + 8);

  float esum = 0.f;

  for (int kt = 0; kt < NT_D; kt++) {
    __syncthreads();
    *(short8*)&Ks[r_st][c_st]     = k_pf0;
    *(short8*)&Ks[r_st][c_st + 8] = k_pf1;
    __syncthreads();
    if (kt + 1 < NT_D) {
      const short* kp = Kh + (size_t)(kbase + (kt + 1) * 64 + r_st) * DK + c_st;
      k_pf0 = *(const short8*)kp;
      k_pf1 = *(const short8*)(kp + 8);
    }
#pragma unroll
    for (int ct = 0; ct < 4; ct++) {
      short8 k0v = *(const short8*)&Ks[ct * 16 + fr][fg * 8];
      short8 k1v = *(const short8*)&Ks[ct * 16 + fr][32 + fg * 8];
      f32x4 zz = {0.f, 0.f, 0.f, 0.f};
      zz = MFMA16(k0v, qa0, zz);   // swapped: lane -> q-row fr, k-cols fg*4+r
      zz = MFMA16(k1v, qa1, zz);
#pragma unroll
      for (int r = 0; r < 4; r++)
        esum += __builtin_amdgcn_exp2f(zz[r] * C1);
    }
  }

  esum += __shfl_xor(esum, 16);
  esum += __shfl_xor(esum, 32);
  if (lane < 16)
    dp[((size_t)z * 16 + bh) * SEQ + q0 + lane] = esum;
}

// ---------------------------------------------------------------------------
// Kernel 2b: fused attention, 512 threads / 8 waves per block sharing one
// 64x64 K tile + V tile. Swapped QK MFMA -> exp2 (folded 1/den) -> packed
// b64 P staging -> attn store via LDS transpose (256B f32x4) -> PV.
// ---------------------------------------------------------------------------
__global__ __launch_bounds__(512) void attn_pv_kernel(
    const short* __restrict__ Q, const short* __restrict__ K, const short* __restrict__ Vt,
    const float* __restrict__ dp, float* __restrict__ attn,
    short* __restrict__ ctxp0, short* __restrict__ ctxp3)
{
  __shared__ short Ks[64][72];
  __shared__ short Vs[64][72];
  __shared__ short P[8][16][72];

  int t = threadIdx.x, lane = t & 63, wave = t >> 6;   // wave 0..7
  int fr = lane & 15, fg = lane >> 4;
  int bh = blockIdx.y, z = blockIdx.z;
  const short* Qh = Q + (size_t)bh * SEQ * DK;
  const short* Kh = K + (size_t)bh * SEQ * DK;
  const short* Vh = Vt + (size_t)bh * DK * SEQ;
  int q0 = blockIdx.x * 128 + wave * 16;
  const int kbase = z * (SEQ / ASPLIT);

  short8 qa0 = *(const short8*)(Qh + (q0 + fr) * DK + fg * 8);
  short8 qa1 = *(const short8*)(Qh + (q0 + fr) * DK + 32 + fg * 8);

  // denominator for this lane's q-row (fr); folded into exp2 as +log2(1/d)
  float dsum = 0.f;
#pragma unroll
  for (int zz = 0; zz < DSPLIT; zz++)
    dsum += dp[((size_t)zz * 16 + bh) * SEQ + q0 + fr];
  float lg2r = -__builtin_amdgcn_logf(dsum);

  // staging split across 512 threads: one short8 of K and one of V each
  int r_st = t >> 3, c_st = (t & 7) * 8;
  int rlo = lane >> 4, c4 = (lane & 15) * 4;

  f32x4 oacc[4] = {};

  const short* kp0 = Kh + (size_t)(kbase + r_st) * DK + c_st;
  const short* vp0 = Vh + (size_t)r_st * SEQ + kbase + c_st;
  short8 k_pf = *(const short8*)kp0;
  short8 v_pf = *(const short8*)vp0;

  for (int kt = 0; kt < NT_A; kt++) {
    int kb = kbase + kt * 64;
    __syncthreads();
    *(short8*)&Ks[r_st][c_st] = k_pf;
    *(short8*)&Vs[r_st][c_st] = v_pf;
    __syncthreads();
    if (kt + 1 < NT_A) {
      k_pf = *(const short8*)(Kh + (size_t)(kb + 64 + r_st) * DK + c_st);
      v_pf = *(const short8*)(Vh + (size_t)r_st * SEQ + kb + 64 + c_st);
    }

    // swapped scores + exp2(fold) -> packed b64 P writes (4 per lane)
#pragma unroll
    for (int ct = 0; ct < 4; ct++) {
      short8 k0v = *(const short8*)&Ks[ct * 16 + fr][fg * 8];
      short8 k1v = *(const short8*)&Ks[ct * 16 + fr][32 + fg * 8];
      f32x4 zz = {0.f, 0.f, 0.f, 0.f};
      zz = MFMA16(k0v, qa0, zz);   // lane -> q-row fr, k-cols ct*16+fg*4..+3
      zz = MFMA16(k1v, qa1, zz);
      short4v pk;
#pragma unroll
      for (int r = 0; r < 4; r++)
        pk[r] = f2bf(__builtin_amdgcn_exp2f(zz[r] * C1 + lg2r));
      *(short4v*)&P[wave][fr][ct * 16 + fg * 4] = pk;
    }
    asm volatile("s_waitcnt lgkmcnt(0)" ::: "memory");

    // attn store: 4 instrs, each 4 rows x 256B contiguous
#pragma unroll
    for (int jr = 0; jr < 4; jr++) {
      int row = jr * 4 + rlo;
      short4v pv4 = *(const short4v*)&P[wave][row][c4];
      f32x4 vv = {bf2f(pv4[0]), bf2f(pv4[1]), bf2f(pv4[2]), bf2f(pv4[3])};
      *(f32x4*)&attn[((size_t)(bh * SEQ + q0 + row)) * SEQ + kb + c4] = vv;
    }

    // PV: oacc[dt] += P(16q x 64k) * V^T(64d x 64k); 8 MFMAs
    short8 pa0 = *(const short8*)&P[wave][fr][fg * 8];
    short8 pa1 = *(const short8*)&P[wave][fr][32 + fg * 8];
#pragma unroll
    for (int dt = 0; dt < 4; dt++) {
      short8 v0 = *(const short8*)&Vs[dt * 16 + fr][fg * 8];
      short8 v1 = *(const short8*)&Vs[dt * 16 + fr][32 + fg * 8];
      oacc[dt] = MFMA16(pa0, v0, oacc[dt]);
      oacc[dt] = MFMA16(pa1, v1, oacc[dt]);
    }
  }

  int b = bh >> 3, h = bh & 7;
  short* cbase = (z < 3) ? (ctxp0 + (size_t)z * NROWS * DM) : ctxp3;
#pragma unroll
  for (int dt = 0; dt < 4; dt++)
#pragma unroll
    for (int r = 0; r < 4; r++) {
      int row = q0 + fg * 4 + r;
      cbase[((size_t)b * SEQ + row) * DM + h * 64 + dt * 16 + fr] = f2bf(oacc[dt][r]);
    }
}

// ---------------------------------------------------------------------------
// Kernel 3: output projection + bias + residual -> x (f32). Wo read as f32
// with inline cvt in staging. A-operand = sum of 4 ctx partials.
// ---------------------------------------------------------------------------
__global__ __launch_bounds__(256) void oproj_kernel(
    const short* __restrict__ ctxp0, const short* __restrict__ ctxp3,
    const float* __restrict__ Wo,
    const float* __restrict__ bias, const float* __restrict__ resid,
    float* __restrict__ xout)
{
  const size_t NPART = (size_t)NROWS * DM;
  __shared__ short As[64][40];
  __shared__ short Bs[64][40];

  int t = threadIdx.x;
  int lane = t & 63, wave = t >> 6;
  int wr = wave >> 1, wc = wave & 1;
  int fr = lane & 15, fg = lane >> 4;
  int m0 = blockIdx.x * 64, n0 = blockIdx.y * 64;
  int lrow = t >> 2, lcol = (t & 3) * 8;

  f32x4 acc[2][2] = {};

  size_t ia0 = (size_t)(m0 + lrow) * DM + lcol;
  short8 a_pf0 = *(const short8*)(ctxp0 + ia0);
  short8 a_pf1 = *(const short8*)(ctxp0 + NPART + ia0);
  short8 a_pf2 = *(const short8*)(ctxp0 + 2 * NPART + ia0);
  short8 a_pf3 = *(const short8*)(ctxp3 + ia0);
  const float* bp0 = Wo + (size_t)(n0 + lrow) * DM + lcol;
  float4 b0f = *(const float4*)bp0, b1f = *(const float4*)(bp0 + 4);

  for (int k0 = 0; k0 < DM; k0 += 32) {
    __syncthreads();
    {
      short8 sv;
#pragma unroll
      for (int j = 0; j < 8; j++)
        sv[j] = f2bf(bf2f(a_pf0[j]) + bf2f(a_pf1[j]) + bf2f(a_pf2[j]) + bf2f(a_pf3[j]));
      *(short8*)&As[lrow][lcol] = sv;
      *(short8*)&Bs[lrow][lcol] = cvt8(b0f, b1f);
    }
    __syncthreads();
    if (k0 + 32 < DM) {
      size_t ia = (size_t)(m0 + lrow) * DM + k0 + 32 + lcol;
      a_pf0 = *(const short8*)(ctxp0 + ia);
      a_pf1 = *(const short8*)(ctxp0 + NPART + ia);
      a_pf2 = *(const short8*)(ctxp0 + 2 * NPART + ia);
      a_pf3 = *(const short8*)(ctxp3 + ia);
      const float* bn = Wo + (size_t)(n0 + lrow) * DM + k0 + 32 + lcol;
      b0f = *(const float4*)bn; b1f = *(const float4*)(bn + 4);
    }
    short8 a0 = *(const short8*)&As[wr * 32 + fr][fg * 8];
    short8 a1 = *(const short8*)&As[wr * 32 + 16 + fr][fg * 8];
    short8 b0 = *(const short8*)&Bs[wc * 32 + fr][fg * 8];
    short8 b1 = *(const short8*)&Bs[wc * 32 + 16 + fr][fg * 8];
    acc[0][0] = MFMA16(a0, b0, acc[0][0]);
    acc[0][1] = MFMA16(a0, b1, acc[0][1]);
    acc[1][0] = MFMA16(a1, b0, acc[1][0]);
    acc[1][1] = MFMA16(a1, b1, acc[1][1]);
  }

#pragma unroll
  for (int mi = 0; mi < 2; mi++)
#pragma unroll
    for (int ni = 0; ni < 2; ni++)
#pragma unroll
      for (int r = 0; r < 4; r++) {
        int row = m0 + wr * 32 + mi * 16 + fg * 4 + r;
        int col = n0 + wc * 32 + ni * 16 + fr;
        float val = acc[mi][ni][r] + bias[col] + resid[(size_t)row * DM + col];
        xout[(size_t)row * DM + col] = val;
      }
}

// ---------------------------------------------------------------------------
// Kernel 4: LayerNorm over last dim (512). One wave per row.
// ---------------------------------------------------------------------------
__global__ __launch_bounds__(256) void ln_kernel(
    const float* __restrict__ x, const float* __restrict__ gamma,
    const float* __restrict__ beta, float* __restrict__ y)
{
  int row = blockIdx.x * 4 + (threadIdx.x >> 6);
  int lane = threadIdx.x & 63;
  const float4* xr = (const float4*)(x + (size_t)row * DM);
  float4 v0 = xr[lane * 2];
  float4 v1 = xr[lane * 2 + 1];
  float s = v0.x + v0.y + v0.z + v0.w + v1.x + v1.y + v1.z + v1.w;
#pragma unroll
  for (int off = 1; off < 64; off <<= 1) s += __shfl_xor(s, off);
  float mean = s * (1.0f / DM);
  float a0 = v0.x - mean, a1 = v0.y - mean, a2 = v0.z - mean, a3 = v0.w - mean;
  float a4 = v1.x - mean, a5 = v1.y - mean, a6 = v1.z - mean, a7 = v1.w - mean;
  float vs = a0 * a0 + a1 * a1 + a2 * a2 + a3 * a3 + a4 * a4 + a5 * a5 + a6 * a6 + a7 * a7;
#pragma unroll
  for (int off = 1; off < 64; off <<= 1) vs += __shfl_xor(vs, off);
  float rstd = rsqrtf(vs * (1.0f / DM) + 1e-5f);
  const float4* gp = (const float4*)gamma;
  const float4* bp = (const float4*)beta;
  float4 g0 = gp[lane * 2], g1 = gp[lane * 2 + 1];
  float4 b0 = bp[lane * 2], b1 = bp[lane * 2 + 1];
  float4 o0, o1;
  o0.x = a0 * rstd * g0.x + b0.x; o0.y = a1 * rstd * g0.y + b0.y;
  o0.z = a2 * rstd * g0.z + b0.z; o0.w = a3 * rstd * g0.w + b0.w;
  o1.x = a4 * rstd * g1.x + b1.x; o1.y = a5 * rstd * g1.y + b1.y;
  o1.z = a6 * rstd * g1.z + b1.z; o1.w = a7 * rstd * g1.w + b1.w;
  float4* yr = (float4*)(y + (size_t)row * DM);
  yr[lane * 2] = o0;
  yr[lane * 2 + 1] = o1;
}

// ---------------------------------------------------------------------------
extern "C" void kernel_launch(void* const* d_in, const int* in_sizes, int n_in,
                              void* d_out, int out_size, void* d_ws, size_t ws_size,
                              hipStream_t stream)
{
  const float* q     = (const float*)d_in[0];
  const float* k     = (const float*)d_in[1];
  const float* v     = (const float*)d_in[2];
  const float* Wq    = (const float*)d_in[3];
  const float* bq    = (const float*)d_in[4];
  const float* Wk    = (const float*)d_in[5];
  const float* bk    = (const float*)d_in[6];
  const float* Wv    = (const float*)d_in[7];
  const float* bv    = (const float*)d_in[8];
  const float* Wo    = (const float*)d_in[9];
  const float* bo    = (const float*)d_in[10];
  const float* gamma = (const float*)d_in[11];
  const float* beta  = (const float*)d_in[12];

  char* w = (char*)d_ws;
  short* Qb    = (short*)(w + ((size_t)12 << 20));    // [12,16)  [B,H,S,DK]
  short* Kb    = (short*)(w + ((size_t)16 << 20));    // [16,20)
  short* Vtb   = (short*)(w + ((size_t)20 << 20));    // [20,24)  [B,H,DK,S]
  float* denp  = (float*)(w + ((size_t)26 << 20));    // [26,26.5) f32 [4][16][SEQ]
  short* ctxp0 = (short*)(w);                         // [ 0,12): partials 0..2
  short* ctxp3 = (short*)(w + ((size_t)27 << 20));    // [27,31): partial 3
  float* xbuf  = (float*)(w + ((size_t)12 << 20));    // [12,20): reuse Qb/Kb (dead)

  float* y = (float*)d_out;
  float* attnp = y + (size_t)NROWS * DM;  // [B,H,S,S]

  qkv_proj_kernel<<<dim3(64, 8, 3), 256, 0, stream>>>(q, k, v, Wq, Wk, Wv,
                                                      bq, bk, bv, Qb, Kb, Vtb);
  den_kernel<<<dim3(32, 16, DSPLIT), 256, 0, stream>>>(Qb, Kb, denp);
  attn_pv_kernel<<<dim3(16, 16, ASPLIT), 512, 0, stream>>>(Qb, Kb, Vtb, denp, attnp,
                                                           ctxp0, ctxp3);
  oproj_kernel<<<dim3(64, 8), 256, 0, stream>>>(ctxp0, ctxp3, Wo, bo, q, xbuf);
  ln_kernel<<<1024, 256, 0, stream>>>(xbuf, gamma, beta, y);
}

// Round 15
// 130.167 us; speedup vs baseline: 1.0083x; 1.0043x over previous
//
#include <hip/hip_runtime.h>
#include <hip/hip_bf16.h>

typedef __attribute__((ext_vector_type(8))) short short8;
typedef __attribute__((ext_vector_type(4))) short short4v;
typedef __attribute__((ext_vector_type(4))) float f32x4;

#define MFMA16(A, B, C) __builtin_amdgcn_mfma_f32_16x16x32_bf16(A, B, C, 0, 0, 0)

#define SEQ 2048
#define DM 512
#define NH 8
#define DK 64
#define NROWS 4096   // B*S
#define DSPLIT 4     // k-splits for den
#define ASPLIT 4     // k-splits for attn_pv
#define NT_D (SEQ / DSPLIT / 64)  // 8 tiles
#define NT_A (SEQ / ASPLIT / 64)  // 8 tiles
#define C1 0.180336880f           // 0.125 * log2(e)

// raw barrier pair: no vmcnt(0) store drain (unlike __syncthreads)
#define CFENCE() asm volatile("" ::: "memory")
#define LGKM0()  asm volatile("s_waitcnt lgkmcnt(0)" ::: "memory")

__device__ __forceinline__ short f2bf(float f) {
  union { float f; unsigned u; } x; x.f = f;
  unsigned r = (x.u + 0x7fffu + ((x.u >> 16) & 1u)) >> 16;
  return (short)r;
}
__device__ __forceinline__ float bf2f(short s) {
  union { unsigned u; float f; } x; x.u = ((unsigned)(unsigned short)s) << 16;
  return x.f;
}
__device__ __forceinline__ short8 cvt8(float4 f0, float4 f1) {
  short8 s;
  s[0] = f2bf(f0.x); s[1] = f2bf(f0.y); s[2] = f2bf(f0.z); s[3] = f2bf(f0.w);
  s[4] = f2bf(f1.x); s[5] = f2bf(f1.y); s[6] = f2bf(f1.z); s[7] = f2bf(f1.w);
  return s;
}

// ---------------------------------------------------------------------------
// Kernel 1: QKV projection from f32 inputs (inline cvt), reg-prefetched
// staging. out[n][o] = sum_d X[n][d]*W[o][d] + b[o]
// z=0: Q -> [B,H,S,DK] ; z=1: K -> [B,H,S,DK] ; z=2: V -> [B,H,DK,S] (T)
// ---------------------------------------------------------------------------
__global__ __launch_bounds__(256) void qkv_proj_kernel(
    const float* __restrict__ qin, const float* __restrict__ kin, const float* __restrict__ vin,
    const float* __restrict__ Wq, const float* __restrict__ Wk, const float* __restrict__ Wv,
    const float* __restrict__ bq, const float* __restrict__ bk, const float* __restrict__ bv,
    short* __restrict__ Qb, short* __restrict__ Kb, short* __restrict__ Vtb)
{
  int z = blockIdx.z;
  const float* X    = (z == 0) ? qin : (z == 1) ? kin : vin;
  const float* W    = (z == 0) ? Wq  : (z == 1) ? Wk  : Wv;
  const float* bias = (z == 0) ? bq  : (z == 1) ? bk  : bv;

  __shared__ short As[64][40];
  __shared__ short Bs[64][40];

  int t = threadIdx.x;
  int lane = t & 63, wave = t >> 6;
  int wr = wave >> 1, wc = wave & 1;
  int fr = lane & 15, fg = lane >> 4;
  int m0 = blockIdx.x * 64, n0 = blockIdx.y * 64;
  int lrow = t >> 2, lcol = (t & 3) * 8;

  f32x4 acc[2][2] = {};

  const float* ap = X + (size_t)(m0 + lrow) * DM + lcol;
  const float* bp = W + (size_t)(n0 + lrow) * DM + lcol;
  float4 a0f = *(const float4*)ap,       a1f = *(const float4*)(ap + 4);
  float4 b0f = *(const float4*)bp,       b1f = *(const float4*)(bp + 4);

  for (int k0 = 0; k0 < DM; k0 += 32) {
    __syncthreads();
    *(short8*)&As[lrow][lcol] = cvt8(a0f, a1f);
    *(short8*)&Bs[lrow][lcol] = cvt8(b0f, b1f);
    __syncthreads();
    if (k0 + 32 < DM) {
      const float* an = X + (size_t)(m0 + lrow) * DM + k0 + 32 + lcol;
      const float* bn = W + (size_t)(n0 + lrow) * DM + k0 + 32 + lcol;
      a0f = *(const float4*)an; a1f = *(const float4*)(an + 4);
      b0f = *(const float4*)bn; b1f = *(const float4*)(bn + 4);
    }
    short8 a0 = *(const short8*)&As[wr * 32 + fr][fg * 8];
    short8 a1 = *(const short8*)&As[wr * 32 + 16 + fr][fg * 8];
    short8 b0 = *(const short8*)&Bs[wc * 32 + fr][fg * 8];
    short8 b1 = *(const short8*)&Bs[wc * 32 + 16 + fr][fg * 8];
    acc[0][0] = MFMA16(a0, b0, acc[0][0]);
    acc[0][1] = MFMA16(a0, b1, acc[0][1]);
    acc[1][0] = MFMA16(a1, b0, acc[1][0]);
    acc[1][1] = MFMA16(a1, b1, acc[1][1]);
  }

#pragma unroll
  for (int mi = 0; mi < 2; mi++)
#pragma unroll
    for (int ni = 0; ni < 2; ni++)
#pragma unroll
      for (int r = 0; r < 4; r++) {
        int row = m0 + wr * 32 + mi * 16 + fg * 4 + r;
        int col = n0 + wc * 32 + ni * 16 + fr;
        float val = acc[mi][ni][r] + bias[col];
        int bb = row >> 11, s = row & 2047, h = col >> 6, dk = col & 63;
        short o = f2bf(val);
        if (z == 0)      Qb[((size_t)(bb * NH + h) * SEQ + s) * DK + dk] = o;
        else if (z == 1) Kb[((size_t)(bb * NH + h) * SEQ + s) * DK + dk] = o;
        else             Vtb[((size_t)(bb * NH + h) * DK + dk) * SEQ + s] = o;
      }
}

// ---------------------------------------------------------------------------
// Kernel 2a: softmax denominators (M=0), swapped QK (lane owns one q-row).
// Raw-barrier loop (no store/load drain at the barrier).
// ---------------------------------------------------------------------------
__global__ __launch_bounds__(256) void den_kernel(
    const short* __restrict__ Q, const short* __restrict__ K, float* __restrict__ dp)
{
  __shared__ short Ks[64][72];

  int t = threadIdx.x, lane = t & 63, wave = t >> 6;
  int fr = lane & 15, fg = lane >> 4;
  int bh = blockIdx.y, z = blockIdx.z;
  const short* Qh = Q + (size_t)bh * SEQ * DK;
  const short* Kh = K + (size_t)bh * SEQ * DK;
  int q0 = blockIdx.x * 64 + wave * 16;
  const int kbase = z * (SEQ / DSPLIT);

  short8 qa0 = *(const short8*)(Qh + (q0 + fr) * DK + fg * 8);
  short8 qa1 = *(const short8*)(Qh + (q0 + fr) * DK + 32 + fg * 8);

  int r_st = t >> 2, c_st = (t & 3) * 16;

  const short* kp0 = Kh + (size_t)(kbase + r_st) * DK + c_st;
  short8 k_pf0 = *(const short8*)kp0;
  short8 k_pf1 = *(const short8*)(kp0 + 8);

  float esum = 0.f;

  for (int kt = 0; kt < NT_D; kt++) {
    CFENCE();
    __builtin_amdgcn_s_barrier();   // prev tile fully consumed (reads done)
    CFENCE();
    *(short8*)&Ks[r_st][c_st]     = k_pf0;
    *(short8*)&Ks[r_st][c_st + 8] = k_pf1;
    LGKM0();
    __builtin_amdgcn_s_barrier();   // writes visible to all waves
    CFENCE();
    if (kt + 1 < NT_D) {
      const short* kp = Kh + (size_t)(kbase + (kt + 1) * 64 + r_st) * DK + c_st;
      k_pf0 = *(const short8*)kp;
      k_pf1 = *(const short8*)(kp + 8);
    }
#pragma unroll
    for (int ct = 0; ct < 4; ct++) {
      short8 k0v = *(const short8*)&Ks[ct * 16 + fr][fg * 8];
      short8 k1v = *(const short8*)&Ks[ct * 16 + fr][32 + fg * 8];
      f32x4 zz = {0.f, 0.f, 0.f, 0.f};
      zz = MFMA16(k0v, qa0, zz);   // swapped: lane -> q-row fr, k-cols fg*4+r
      zz = MFMA16(k1v, qa1, zz);
#pragma unroll
      for (int r = 0; r < 4; r++)
        esum += __builtin_amdgcn_exp2f(zz[r] * C1);
    }
  }

  esum += __shfl_xor(esum, 16);
  esum += __shfl_xor(esum, 32);
  if (lane < 16)
    dp[((size_t)z * 16 + bh) * SEQ + q0 + lane] = esum;
}

// ---------------------------------------------------------------------------
// Kernel 2b: fused attention, 512 threads / 8 waves per block sharing one
// 64x64 K tile + V tile. RAW BARRIERS: attn stores stay in flight across
// tiles (no vmcnt(0) drain). Swapped QK MFMA -> exp2 (folded 1/den) ->
// packed b64 P staging -> attn store via LDS transpose (256B f32x4) -> PV.
// ---------------------------------------------------------------------------
__global__ __launch_bounds__(512) void attn_pv_kernel(
    const short* __restrict__ Q, const short* __restrict__ K, const short* __restrict__ Vt,
    const float* __restrict__ dp, float* __restrict__ attn,
    short* __restrict__ ctxp0, short* __restrict__ ctxp3)
{
  __shared__ short Ks[64][72];
  __shared__ short Vs[64][72];
  __shared__ short P[8][16][72];

  int t = threadIdx.x, lane = t & 63, wave = t >> 6;   // wave 0..7
  int fr = lane & 15, fg = lane >> 4;
  int bh = blockIdx.y, z = blockIdx.z;
  const short* Qh = Q + (size_t)bh * SEQ * DK;
  const short* Kh = K + (size_t)bh * SEQ * DK;
  const short* Vh = Vt + (size_t)bh * DK * SEQ;
  int q0 = blockIdx.x * 128 + wave * 16;
  const int kbase = z * (SEQ / ASPLIT);

  short8 qa0 = *(const short8*)(Qh + (q0 + fr) * DK + fg * 8);
  short8 qa1 = *(const short8*)(Qh + (q0 + fr) * DK + 32 + fg * 8);

  // denominator for this lane's q-row (fr); folded into exp2 as +log2(1/d)
  float dsum = 0.f;
#pragma unroll
  for (int zz = 0; zz < DSPLIT; zz++)
    dsum += dp[((size_t)zz * 16 + bh) * SEQ + q0 + fr];
  float lg2r = -__builtin_amdgcn_logf(dsum);

  // staging split across 512 threads: one short8 of K and one of V each
  int r_st = t >> 3, c_st = (t & 7) * 8;
  int rlo = lane >> 4, c4 = (lane & 15) * 4;

  f32x4 oacc[4] = {};

  const short* kp0 = Kh + (size_t)(kbase + r_st) * DK + c_st;
  const short* vp0 = Vh + (size_t)r_st * SEQ + kbase + c_st;
  short8 k_pf = *(const short8*)kp0;
  short8 v_pf = *(const short8*)vp0;

  for (int kt = 0; kt < NT_A; kt++) {
    int kb = kbase + kt * 64;
    CFENCE();
    __builtin_amdgcn_s_barrier();   // all waves done reading prev Ks/Vs
    CFENCE();
    *(short8*)&Ks[r_st][c_st] = k_pf;   // compiler waits (counted) on k_pf/v_pf loads
    *(short8*)&Vs[r_st][c_st] = v_pf;
    LGKM0();
    __builtin_amdgcn_s_barrier();   // LDS writes visible; stores NOT drained
    CFENCE();
    if (kt + 1 < NT_A) {
      k_pf = *(const short8*)(Kh + (size_t)(kb + 64 + r_st) * DK + c_st);
      v_pf = *(const short8*)(Vh + (size_t)r_st * SEQ + kb + 64 + c_st);
    }

    // swapped scores + exp2(fold) -> packed b64 P writes (4 per lane)
#pragma unroll
    for (int ct = 0; ct < 4; ct++) {
      short8 k0v = *(const short8*)&Ks[ct * 16 + fr][fg * 8];
      short8 k1v = *(const short8*)&Ks[ct * 16 + fr][32 + fg * 8];
      f32x4 zz = {0.f, 0.f, 0.f, 0.f};
      zz = MFMA16(k0v, qa0, zz);   // lane -> q-row fr, k-cols ct*16+fg*4..+3
      zz = MFMA16(k1v, qa1, zz);
      short4v pk;
#pragma unroll
      for (int r = 0; r < 4; r++)
        pk[r] = f2bf(__builtin_amdgcn_exp2f(zz[r] * C1 + lg2r));
      *(short4v*)&P[wave][fr][ct * 16 + fg * 4] = pk;
    }
    LGKM0();

    // attn store: 4 instrs, each 4 rows x 256B contiguous (fire-and-forget)
#pragma unroll
    for (int jr = 0; jr < 4; jr++) {
      int row = jr * 4 + rlo;
      short4v pv4 = *(const short4v*)&P[wave][row][c4];
      f32x4 vv = {bf2f(pv4[0]), bf2f(pv4[1]), bf2f(pv4[2]), bf2f(pv4[3])};
      *(f32x4*)&attn[((size_t)(bh * SEQ + q0 + row)) * SEQ + kb + c4] = vv;
    }

    // PV: oacc[dt] += P(16q x 64k) * V^T(64d x 64k); 8 MFMAs
    short8 pa0 = *(const short8*)&P[wave][fr][fg * 8];
    short8 pa1 = *(const short8*)&P[wave][fr][32 + fg * 8];
#pragma unroll
    for (int dt = 0; dt < 4; dt++) {
      short8 v0 = *(const short8*)&Vs[dt * 16 + fr][fg * 8];
      short8 v1 = *(const short8*)&Vs[dt * 16 + fr][32 + fg * 8];
      oacc[dt] = MFMA16(pa0, v0, oacc[dt]);
      oacc[dt] = MFMA16(pa1, v1, oacc[dt]);
    }
  }

  int b = bh >> 3, h = bh & 7;
  short* cbase = (z < 3) ? (ctxp0 + (size_t)z * NROWS * DM) : ctxp3;
#pragma unroll
  for (int dt = 0; dt < 4; dt++)
#pragma unroll
    for (int r = 0; r < 4; r++) {
      int row = q0 + fg * 4 + r;
      cbase[((size_t)b * SEQ + row) * DM + h * 64 + dt * 16 + fr] = f2bf(oacc[dt][r]);
    }
}

// ---------------------------------------------------------------------------
// Kernel 3: output projection + bias + residual -> x (f32). Wo read as f32
// with inline cvt in staging. A-operand = sum of 4 ctx partials.
// ---------------------------------------------------------------------------
__global__ __launch_bounds__(256) void oproj_kernel(
    const short* __restrict__ ctxp0, const short* __restrict__ ctxp3,
    const float* __restrict__ Wo,
    const float* __restrict__ bias, const float* __restrict__ resid,
    float* __restrict__ xout)
{
  const size_t NPART = (size_t)NROWS * DM;
  __shared__ short As[64][40];
  __shared__ short Bs[64][40];

  int t = threadIdx.x;
  int lane = t & 63, wave = t >> 6;
  int wr = wave >> 1, wc = wave & 1;
  int fr = lane & 15, fg = lane >> 4;
  int m0 = blockIdx.x * 64, n0 = blockIdx.y * 64;
  int lrow = t >> 2, lcol = (t & 3) * 8;

  f32x4 acc[2][2] = {};

  size_t ia0 = (size_t)(m0 + lrow) * DM + lcol;
  short8 a_pf0 = *(const short8*)(ctxp0 + ia0);
  short8 a_pf1 = *(const short8*)(ctxp0 + NPART + ia0);
  short8 a_pf2 = *(const short8*)(ctxp0 + 2 * NPART + ia0);
  short8 a_pf3 = *(const short8*)(ctxp3 + ia0);
  const float* bp0 = Wo + (size_t)(n0 + lrow) * DM + lcol;
  float4 b0f = *(const float4*)bp0, b1f = *(const float4*)(bp0 + 4);

  for (int k0 = 0; k0 < DM; k0 += 32) {
    __syncthreads();
    {
      short8 sv;
#pragma unroll
      for (int j = 0; j < 8; j++)
        sv[j] = f2bf(bf2f(a_pf0[j]) + bf2f(a_pf1[j]) + bf2f(a_pf2[j]) + bf2f(a_pf3[j]));
      *(short8*)&As[lrow][lcol] = sv;
      *(short8*)&Bs[lrow][lcol] = cvt8(b0f, b1f);
    }
    __syncthreads();
    if (k0 + 32 < DM) {
      size_t ia = (size_t)(m0 + lrow) * DM + k0 + 32 + lcol;
      a_pf0 = *(const short8*)(ctxp0 + ia);
      a_pf1 = *(const short8*)(ctxp0 + NPART + ia);
      a_pf2 = *(const short8*)(ctxp0 + 2 * NPART + ia);
      a_pf3 = *(const short8*)(ctxp3 + ia);
      const float* bn = Wo + (size_t)(n0 + lrow) * DM + k0 + 32 + lcol;
      b0f = *(const float4*)bn; b1f = *(const float4*)(bn + 4);
    }
    short8 a0 = *(const short8*)&As[wr * 32 + fr][fg * 8];
    short8 a1 = *(const short8*)&As[wr * 32 + 16 + fr][fg * 8];
    short8 b0 = *(const short8*)&Bs[wc * 32 + fr][fg * 8];
    short8 b1 = *(const short8*)&Bs[wc * 32 + 16 + fr][fg * 8];
    acc[0][0] = MFMA16(a0, b0, acc[0][0]);
    acc[0][1] = MFMA16(a0, b1, acc[0][1]);
    acc[1][0] = MFMA16(a1, b0, acc[1][0]);
    acc[1][1] = MFMA16(a1, b1, acc[1][1]);
  }

#pragma unroll
  for (int mi = 0; mi < 2; mi++)
#pragma unroll
    for (int ni = 0; ni < 2; ni++)
#pragma unroll
      for (int r = 0; r < 4; r++) {
        int row = m0 + wr * 32 + mi * 16 + fg * 4 + r;
        int col = n0 + wc * 32 + ni * 16 + fr;
        float val = acc[mi][ni][r] + bias[col] + resid[(size_t)row * DM + col];
        xout[(size_t)row * DM + col] = val;
      }
}

// ---------------------------------------------------------------------------
// Kernel 4: LayerNorm over last dim (512). One wave per row.
// ---------------------------------------------------------------------------
__global__ __launch_bounds__(256) void ln_kernel(
    const float* __restrict__ x, const float* __restrict__ gamma,
    const float* __restrict__ beta, float* __restrict__ y)
{
  int row = blockIdx.x * 4 + (threadIdx.x >> 6);
  int lane = threadIdx.x & 63;
  const float4* xr = (const float4*)(x + (size_t)row * DM);
  float4 v0 = xr[lane * 2];
  float4 v1 = xr[lane * 2 + 1];
  float s = v0.x + v0.y + v0.z + v0.w + v1.x + v1.y + v1.z + v1.w;
#pragma unroll
  for (int off = 1; off < 64; off <<= 1) s += __shfl_xor(s, off);
  float mean = s * (1.0f / DM);
  float a0 = v0.x - mean, a1 = v0.y - mean, a2 = v0.z - mean, a3 = v0.w - mean;
  float a4 = v1.x - mean, a5 = v1.y - mean, a6 = v1.z - mean, a7 = v1.w - mean;
  float vs = a0 * a0 + a1 * a1 + a2 * a2 + a3 * a3 + a4 * a4 + a5 * a5 + a6 * a6 + a7 * a7;
#pragma unroll
  for (int off = 1; off < 64; off <<= 1) vs += __shfl_xor(vs, off);
  float rstd = rsqrtf(vs * (1.0f / DM) + 1e-5f);
  const float4* gp = (const float4*)gamma;
  const float4* bp = (const float4*)beta;
  float4 g0 = gp[lane * 2], g1 = gp[lane * 2 + 1];
  float4 b0 = bp[lane * 2], b1 = bp[lane * 2 + 1];
  float4 o0, o1;
  o0.x = a0 * rstd * g0.x + b0.x; o0.y = a1 * rstd * g0.y + b0.y;
  o0.z = a2 * rstd * g0.z + b0.z; o0.w = a3 * rstd * g0.w + b0.w;
  o1.x = a4 * rstd * g1.x + b1.x; o1.y = a5 * rstd * g1.y + b1.y;
  o1.z = a6 * rstd * g1.z + b1.z; o1.w = a7 * rstd * g1.w + b1.w;
  float4* yr = (float4*)(y + (size_t)row * DM);
  yr[lane * 2] = o0;
  yr[lane * 2 + 1] = o1;
}

// ---------------------------------------------------------------------------
extern "C" void kernel_launch(void* const* d_in, const int* in_sizes, int n_in,
                              void* d_out, int out_size, void* d_ws, size_t ws_size,
                              hipStream_t stream)
{
  const float* q     = (const float*)d_in[0];
  const float* k     = (const float*)d_in[1];
  const float* v     = (const float*)d_in[2];
  const float* Wq    = (const float*)d_in[3];
  const float* bq    = (const float*)d_in[4];
  const float* Wk    = (const float*)d_in[5];
  const float* bk    = (const float*)d_in[6];
  const float* Wv    = (const float*)d_in[7];
  const float* bv    = (const float*)d_in[8];
  const float* Wo    = (const float*)d_in[9];
  const float* bo    = (const float*)d_in[10];
  const float* gamma = (const float*)d_in[11];
  const float* beta  = (const float*)d_in[12];

  char* w = (char*)d_ws;
  short* Qb    = (short*)(w + ((size_t)12 << 20));    // [12,16)  [B,H,S,DK]
  short* Kb    = (short*)(w + ((size_t)16 << 20));    // [16,20)
  short* Vtb   = (short*)(w + ((size_t)20 << 20));    // [20,24)  [B,H,DK,S]
  float* denp  = (float*)(w + ((size_t)26 << 20));    // [26,26.5) f32 [4][16][SEQ]
  short* ctxp0 = (short*)(w);                         // [ 0,12): partials 0..2
  short* ctxp3 = (short*)(w + ((size_t)27 << 20));    // [27,31): partial 3
  float* xbuf  = (float*)(w + ((size_t)12 << 20));    // [12,20): reuse Qb/Kb (dead)

  float* y = (float*)d_out;
  float* attnp = y + (size_t)NROWS * DM;  // [B,H,S,S]

  qkv_proj_kernel<<<dim3(64, 8, 3), 256, 0, stream>>>(q, k, v, Wq, Wk, Wv,
                                                      bq, bk, bv, Qb, Kb, Vtb);
  den_kernel<<<dim3(32, 16, DSPLIT), 256, 0, stream>>>(Qb, Kb, denp);
  attn_pv_kernel<<<dim3(16, 16, ASPLIT), 512, 0, stream>>>(Qb, Kb, Vtb, denp, attnp,
                                                           ctxp0, ctxp3);
  oproj_kernel<<<dim3(64, 8), 256, 0, stream>>>(ctxp0, ctxp3, Wo, bo, q, xbuf);
  ln_kernel<<<1024, 256, 0, stream>>>(xbuf, gamma, beta, y);
}